// Round 6
// baseline (273.725 us; speedup 1.0000x reference)
//
#include <hip/hip_runtime.h>
#include <hip/hip_bf16.h>

// FraudDetectionHybrid: h1=tanh(x@W1^T+b1); h2=tanh(h1@W2^T+b2);
// sq_ij=|h2_i|^2+|h2_j|^2-2*h2_i.h2_j; out=exp(-g*sq)@Wc^T+bc
// GEMM1/2: MX-fp8 (e4m3, unit block-scales, data pre-scaled by 2^k),
// 256x256, BK=128 staged as two 64B-row k-half sub-tiles (bank-conflict-free
// geometry), 3 asm barriers/tile, counted vmcnt(8). Gram: bf16 triangular.

#define NROWS 4096
#define HID   4096
#define INDIM 512
#define GAMMA_F 5e-4f

typedef float f32x4  __attribute__((ext_vector_type(4)));
typedef float f32x16 __attribute__((ext_vector_type(16)));
typedef short bf16x8 __attribute__((ext_vector_type(8)));
typedef int   i32x4  __attribute__((ext_vector_type(4)));
typedef int   i32x8  __attribute__((ext_vector_type(8)));

#define BAR() asm volatile("s_barrier" ::: "memory")
#define SCALE1 0x7F7F7F7F   // e8m0 = 127 -> 2^0 in all bytes; opsel-independent

__device__ __forceinline__ unsigned short f2bf_rne(float f) {
  union { float f; unsigned int u; } v; v.f = f;
  unsigned int r = v.u + 0x7FFFu + ((v.u >> 16) & 1u);
  return (unsigned short)(r >> 16);
}
__device__ __forceinline__ float bf2f(unsigned short u) {
  union { unsigned int u; float f; } v; v.u = ((unsigned int)u) << 16; return v.f;
}

// f32 -> OCP e4m3fn, RNE, saturate to 448, subnormals handled
__device__ __forceinline__ unsigned char f2e4m3(float x) {
  unsigned int u = __float_as_uint(x);
  unsigned char s = (unsigned char)((u >> 24) & 0x80u);
  float a = fabsf(x);
  if (a >= 448.f) return s | 0x7E;
  if (a < 0.015625f) {                      // below 2^-6: subnormal (2^-9 ulp)
    int q = (int)rintf(a * 512.f);          // 0..8 (8 == 2^-6 encodes as 0x08)
    return s | (unsigned char)q;
  }
  unsigned int ua = u & 0x7fffffffu;
  ua += 0x7FFFFu + ((ua >> 20) & 1u);       // RNE at mantissa bit 20
  int e = (int)(ua >> 23) - 127;            // -6..8
  unsigned int m = (ua >> 20) & 7u;
  return s | (unsigned char)(((e + 7) << 3) | m);
}

__global__ void cast_f32_fp8(const float* __restrict__ src,
                             unsigned char* __restrict__ dst,
                             float scale, int n8) {
  int i = blockIdx.x * blockDim.x + threadIdx.x;
  if (i >= n8) return;
  const float4* s = (const float4*)src;
  float4 v0 = s[i * 2], v1 = s[i * 2 + 1];
  unsigned int r0 = (unsigned int)f2e4m3(v0.x * scale)
                  | ((unsigned int)f2e4m3(v0.y * scale) << 8)
                  | ((unsigned int)f2e4m3(v0.z * scale) << 16)
                  | ((unsigned int)f2e4m3(v0.w * scale) << 24);
  unsigned int r1 = (unsigned int)f2e4m3(v1.x * scale)
                  | ((unsigned int)f2e4m3(v1.y * scale) << 8)
                  | ((unsigned int)f2e4m3(v1.z * scale) << 16)
                  | ((unsigned int)f2e4m3(v1.w * scale) << 24);
  uint2 o; o.x = r0; o.y = r1;
  ((uint2*)dst)[i] = o;
}

__global__ void init_vecs(float* __restrict__ out, float* __restrict__ norms,
                          const float* __restrict__ bc, int n) {
  int i = blockIdx.x * blockDim.x + threadIdx.x;
  if (i < n) { out[i] = bc[0]; norms[i] = 0.f; }
}

__device__ __forceinline__ void gload16(const void* g, void* l) {
  __builtin_amdgcn_global_load_lds(
      (const __attribute__((address_space(1))) void*)g,
      (__attribute__((address_space(3))) void*)l, 16, 0, 0);
}

// ---------------------------------------------------------------------------
// fp8 NT GEMM: D = A[M,K]*B[N,K]^T (e4m3 bytes). BM=BN=256, BK=128 B,
// 8 waves (2Mx4N), per-wave 128x64 = 4mi x 2nj fragments of 32x32, K-step 64.
// LDS: [dbuf][khalf][256 rows x 64 B] per matrix = 128 KiB total.
//   64B rows -> bank = 16*(row&1) + 4*chunk: the PROVEN zero-conflict
//   geometry (R1-R4). Swizzle: chunk c of row r holds global chunk
//   c ^ ((r>>1)&3) (involution; pre-swizzled global src, linear LDS dest).
// 3 barriers/K-tile:
//   reads A01+B (16 b128) | lgkm,BAR | stage B(t+2) | 8 MFMA
//   reads A23   (8 b128)  | lgkm,BAR | stage A(t+2) | 8 MFMA | vmcnt(8),BAR
// MFMA: mfma_scale_f32_32x32x64_f8f6f4, unit scales.
// EPI 0: Hout(fp8) = e4m3(8*tanh(acc/512 + bias));
// EPI 2: Hout(bf16) = bf16(tanh(acc/1024 + bias)) + fused row-norm atomics.
// ---------------------------------------------------------------------------
template <int EPI>
__global__ __launch_bounds__(512, 2)
void gemm256_fp8(const unsigned char* __restrict__ A, const unsigned char* __restrict__ B,
                 int K, int N,
                 const float* __restrict__ bias, void* __restrict__ Hout_,
                 float* __restrict__ norms_out) {
  __shared__ __align__(16) unsigned char As[2][2][256 * 64];
  __shared__ __align__(16) unsigned char Bs[2][2][256 * 64];

  const int tid  = threadIdx.x;
  const int lane = tid & 63;
  const int wave = tid >> 6;
  const int wr = wave >> 2, wc = wave & 3;   // 2x4 wave grid, 128x64 out each
  const int l31 = lane & 31, lh = lane >> 5;

  const int nwg = gridDim.x;
  const int cpx = nwg >> 3;
  const int bid = blockIdx.x;
  const int swz = (bid & 7) * cpx + (bid >> 3);
  const int nbx = N >> 8;
  const int brow = (swz / nbx) << 8;
  const int bcol = (swz % nbx) << 8;

  // staging map: 4 rounds x 512 thr x 16B = 32 KiB tile per matrix.
  // chunk idx = q*512+tid -> kh = idx>>10, row = (idx>>2)&255, c = idx&3.
  // LDS linear dest; global col pre-swizzled: c ^ ((row>>1)&3).
  const unsigned char* ap[4]; const unsigned char* bp[4]; int ldq[4];
#pragma unroll
  for (int q = 0; q < 4; ++q) {
    int idx = q * 512 + tid;
    int kh  = idx >> 10;
    int row = (idx >> 2) & 255;
    int c   = idx & 3;
    int gcol = kh * 64 + (((c ^ ((row >> 1) & 3))) << 4);
    ap[q] = A + (size_t)(brow + row) * K + gcol;
    bp[q] = B + (size_t)(bcol + row) * K + gcol;
    ldq[q] = (q * 512 + wave * 64) * 16;     // wave-uniform LDS byte base
  }
#define STAGE_A(p, tt) do { int kk = (tt) * 128;              \
    gload16(ap[0] + kk, &As[p][0][0] + ldq[0]);               \
    gload16(ap[1] + kk, &As[p][0][0] + ldq[1]);               \
    gload16(ap[2] + kk, &As[p][0][0] + ldq[2]);               \
    gload16(ap[3] + kk, &As[p][0][0] + ldq[3]); } while (0)
#define STAGE_B(p, tt) do { int kk = (tt) * 128;              \
    gload16(bp[0] + kk, &Bs[p][0][0] + ldq[0]);               \
    gload16(bp[1] + kk, &Bs[p][0][0] + ldq[1]);               \
    gload16(bp[2] + kk, &Bs[p][0][0] + ldq[2]);               \
    gload16(bp[3] + kk, &Bs[p][0][0] + ldq[3]); } while (0)

  // fragment offsets within a [256][64] sub-tile: lane (row=base+l31, lh)
  // reads global chunks 2lh, 2lh+1 -> LDS chunks (2lh)^swz, ((2lh)^swz)^1
  int aoff[4], boff[2];
#pragma unroll
  for (int mi = 0; mi < 4; ++mi) {
    int row = wr * 128 + mi * 32 + l31;
    aoff[mi] = row * 64 + ((((lh << 1)) ^ ((row >> 1) & 3)) << 4);
  }
#pragma unroll
  for (int nj = 0; nj < 2; ++nj) {
    int row = wc * 64 + nj * 32 + l31;
    boff[nj] = row * 64 + ((((lh << 1)) ^ ((row >> 1) & 3)) << 4);
  }

#define LDFRAG(dst, base, off) do {                                 \
    i32x4 lo_ = *(const i32x4*)((base) + (off));                    \
    i32x4 hi_ = *(const i32x4*)((base) + ((off) ^ 16));             \
    dst[0]=lo_[0]; dst[1]=lo_[1]; dst[2]=lo_[2]; dst[3]=lo_[3];     \
    dst[4]=hi_[0]; dst[5]=hi_[1]; dst[6]=hi_[2]; dst[7]=hi_[3]; } while (0)

#define MFMA8(d, a, b) \
    d = __builtin_amdgcn_mfma_scale_f32_32x32x64_f8f6f4( \
        a, b, d, 0, 0, 0, SCALE1, 0, SCALE1)

  const int NT = K >> 7;   // K-tiles of 128 bytes (NT even for all our K)

  // prologue: tiles 0,1 fully staged (16 loads/thread)
  STAGE_A(0, 0); STAGE_B(0, 0);
  STAGE_A(1, 1); STAGE_B(1, 1);
  asm volatile("s_waitcnt vmcnt(8)" ::: "memory");   // tile0's 8 landed
  BAR();

  f32x16 acc[4][2] = {};
  i32x8 afr[2][2], bfr[2][2];

  for (int t = 0; t < NT; ++t) {
    const int p = t & 1;
    int t2 = t + 2; if (t2 >= NT) t2 -= NT;   // wrapped dummy keeps counts uniform

    // ---- S1: read A mi0-1 + B nj0-1, both ks (16 b128) ----
#pragma unroll
    for (int mi = 0; mi < 2; ++mi)
#pragma unroll
      for (int ks = 0; ks < 2; ++ks)
        LDFRAG(afr[mi][ks], &As[p][ks][0], aoff[mi]);
#pragma unroll
    for (int nj = 0; nj < 2; ++nj)
#pragma unroll
      for (int ks = 0; ks < 2; ++ks)
        LDFRAG(bfr[nj][ks], &Bs[p][ks][0], boff[nj]);
    asm volatile("s_waitcnt lgkmcnt(0)" ::: "memory");  // my reads done
    BAR();                                              // all waves' B (and A01) reads done
    STAGE_B(p, t2);                                     // safe: overwrite Bs[p]
    __builtin_amdgcn_sched_barrier(0);
    __builtin_amdgcn_s_setprio(1);
#pragma unroll
    for (int ks = 0; ks < 2; ++ks)
#pragma unroll
      for (int mi = 0; mi < 2; ++mi)
#pragma unroll
        for (int nj = 0; nj < 2; ++nj)
          MFMA8(acc[mi][nj], afr[mi][ks], bfr[nj][ks]);
    __builtin_amdgcn_s_setprio(0);

    // ---- S2: read A mi2-3 (8 b128, reuse afr) ----
#pragma unroll
    for (int mi = 0; mi < 2; ++mi)
#pragma unroll
      for (int ks = 0; ks < 2; ++ks)
        LDFRAG(afr[mi][ks], &As[p][ks][0], aoff[2 + mi]);
    asm volatile("s_waitcnt lgkmcnt(0)" ::: "memory");
    BAR();                                              // all waves' A reads done
    STAGE_A(p, t2);                                     // safe: overwrite As[p]
    __builtin_amdgcn_sched_barrier(0);
    __builtin_amdgcn_s_setprio(1);
#pragma unroll
    for (int ks = 0; ks < 2; ++ks)
#pragma unroll
      for (int mi = 0; mi < 2; ++mi)
#pragma unroll
        for (int nj = 0; nj < 2; ++nj)
          MFMA8(acc[2 + mi][nj], afr[mi][ks], bfr[nj][ks]);
    __builtin_amdgcn_s_setprio(0);
    asm volatile("s_waitcnt vmcnt(8)" ::: "memory");    // t+1's 8 loads landed
    BAR();
  }
  asm volatile("s_waitcnt vmcnt(0)" ::: "memory");

  // C/D layout (32x32, shape-determined, m74/m101): col = lane&31,
  // row = (reg&3) + 8*(reg>>2) + 4*(lane>>5)
  const float rescale = (EPI == 0) ? (1.f / 512.f) : (1.f / 1024.f);
  float bv[2];
#pragma unroll
  for (int nj = 0; nj < 2; ++nj) bv[nj] = bias[bcol + wc * 64 + nj * 32 + l31];

#pragma unroll
  for (int mi = 0; mi < 4; ++mi) {
    int rbase = brow + wr * 128 + mi * 32 + 4 * lh;
#pragma unroll
    for (int g = 0; g < 4; ++g) {
#pragma unroll
      for (int h = 0; h < 4; ++h) {
        int reg = g * 4 + h;
        int row = rbase + h + 8 * g;
        float ns = 0.f;
#pragma unroll
        for (int nj = 0; nj < 2; ++nj) {
          int col = bcol + wc * 64 + nj * 32 + l31;
          float v = tanhf(acc[mi][nj][reg] * rescale + bv[nj]);
          if (EPI == 0) {
            ((unsigned char*)Hout_)[(size_t)row * N + col] = f2e4m3(8.f * v);
          } else {
            unsigned short q = f2bf_rne(v);
            ((unsigned short*)Hout_)[(size_t)row * N + col] = q;
            float vq = bf2f(q);
            ns += vq * vq;
          }
        }
        if (EPI == 2) {
          ns += __shfl_xor(ns, 1);
          ns += __shfl_xor(ns, 2);
          ns += __shfl_xor(ns, 4);
          ns += __shfl_xor(ns, 8);
          ns += __shfl_xor(ns, 16);
          if (l31 == 0) atomicAdd(&norms_out[row], ns);
        }
      }
    }
  }
#undef STAGE_A
#undef STAGE_B
#undef LDFRAG
#undef MFMA8
}

// ---------------------------------------------------------------------------
// Triangular gram, bf16 (verified R3 kernel): 128x128 tiles over the lower
// triangle (528 blocks); each exp feeds out[row] AND out[col].
// ---------------------------------------------------------------------------
__global__ __launch_bounds__(256, 2)
void gram_tri(const unsigned short* __restrict__ H, int K,
              const float* __restrict__ norms, const float* __restrict__ Wc,
              float* __restrict__ out) {
  __shared__ __align__(16) unsigned short As[128 * 32];
  __shared__ __align__(16) unsigned short Bs[128 * 32];

  const int tid  = threadIdx.x;
  const int lane = tid & 63;
  const int wave = tid >> 6;
  const int wr = wave >> 1, wc = wave & 1;
  const int fr = lane & 15, fq = lane >> 4;

  const int bid = blockIdx.x;
  const int swz = (bid & 7) * 66 + (bid >> 3);
  int I = (int)((sqrtf(8.0f * (float)swz + 1.0f) - 1.0f) * 0.5f);
  while ((I + 1) * (I + 2) / 2 <= swz) ++I;
  while (I * (I + 1) / 2 > swz) --I;
  const int J = swz - I * (I + 1) / 2;
  const int brow = I << 7, bcol = J << 7;
  const bool diag = (I == J);

  f32x4 acc[4][4] = {};

  for (int k0 = 0; k0 < K; k0 += 32) {
    __syncthreads();
#pragma unroll
    for (int q = 0; q < 2; ++q) {
      int idx = q * 256 + tid;
      int row = idx >> 2, c = idx & 3;
      int col = (c ^ ((row >> 1) & 3)) << 3;
      gload16(H + (size_t)(brow + row) * K + k0 + col, &As[(q * 256 + wave * 64) * 8]);
      gload16(H + (size_t)(bcol + row) * K + k0 + col, &Bs[(q * 256 + wave * 64) * 8]);
    }
    __syncthreads();

    bf16x8 af[4], bfrag[4];
#pragma unroll
    for (int mi = 0; mi < 4; ++mi) {
      int row = wr * 64 + mi * 16 + fr;
      af[mi] = *(const bf16x8*)&As[row * 32 + ((fq ^ ((row >> 1) & 3)) << 3)];
    }
#pragma unroll
    for (int nj = 0; nj < 4; ++nj) {
      int row = wc * 64 + nj * 16 + fr;
      bfrag[nj] = *(const bf16x8*)&Bs[row * 32 + ((fq ^ ((row >> 1) & 3)) << 3)];
    }
#pragma unroll
    for (int mi = 0; mi < 4; ++mi)
#pragma unroll
      for (int nj = 0; nj < 4; ++nj)
        acc[mi][nj] = __builtin_amdgcn_mfma_f32_16x16x32_bf16(af[mi], bfrag[nj], acc[mi][nj], 0, 0, 0);
  }

  float ncol[4], wcv[4];
#pragma unroll
  for (int nj = 0; nj < 4; ++nj) {
    int col = bcol + wc * 64 + nj * 16 + fr;
    ncol[nj] = norms[col];
    wcv[nj]  = Wc[col];
  }
  float colpart[4] = {0.f, 0.f, 0.f, 0.f};
#pragma unroll
  for (int mi = 0; mi < 4; ++mi) {
    int row0 = brow + wr * 64 + mi * 16 + fq * 4;
    float4 nr4  = *(const float4*)&norms[row0];
    float4 wcr4 = *(const float4*)&Wc[row0];
#pragma unroll
    for (int rr = 0; rr < 4; ++rr) {
      float nrow = (rr == 0) ? nr4.x : (rr == 1) ? nr4.y : (rr == 2) ? nr4.z : nr4.w;
      float wrow = (rr == 0) ? wcr4.x : (rr == 1) ? wcr4.y : (rr == 2) ? wcr4.z : wcr4.w;
      float rowpart = 0.f;
#pragma unroll
      for (int nj = 0; nj < 4; ++nj) {
        float sq = nrow + ncol[nj] - 2.0f * acc[mi][nj][rr];
        float e = __expf(-GAMMA_F * sq);
        rowpart += e * wcv[nj];
        colpart[nj] += e * wrow;
      }
      rowpart += __shfl_xor(rowpart, 1);
      rowpart += __shfl_xor(rowpart, 2);
      rowpart += __shfl_xor(rowpart, 4);
      rowpart += __shfl_xor(rowpart, 8);
      if (fr == 0) atomicAdd(&out[row0 + rr], rowpart);
    }
  }
  if (!diag) {
#pragma unroll
    for (int nj = 0; nj < 4; ++nj) {
      colpart[nj] += __shfl_xor(colpart[nj], 16);
      colpart[nj] += __shfl_xor(colpart[nj], 32);
      if (fq == 0) atomicAdd(&out[bcol + wc * 64 + nj * 16 + fr], colpart[nj]);
    }
  }
}

extern "C" void kernel_launch(void* const* d_in, const int* in_sizes, int n_in,
                              void* d_out, int out_size, void* d_ws, size_t ws_size,
                              hipStream_t stream) {
  const float* x  = (const float*)d_in[0];  // [4096,512]
  const float* W1 = (const float*)d_in[1];  // [4096,512]
  const float* b1 = (const float*)d_in[2];  // [4096]
  const float* W2 = (const float*)d_in[3];  // [4096,4096]
  const float* b2 = (const float*)d_in[4];  // [4096]
  const float* Wc = (const float*)d_in[5];  // [1,4096]
  const float* bc = (const float*)d_in[6];  // [1]
  float* out = (float*)d_out;               // [4096,1]

  char* ws = (char*)d_ws;
  unsigned char* xq  = (unsigned char*)ws; ws += (size_t)NROWS * INDIM;   // x*16   fp8
  unsigned char* w1q = (unsigned char*)ws; ws += (size_t)HID * INDIM;     // W1*32  fp8
  unsigned char* w2q = (unsigned char*)ws; ws += (size_t)HID * HID;       // W2*128 fp8
  unsigned char* h1q = (unsigned char*)ws; ws += (size_t)NROWS * HID;     // h1*8   fp8
  unsigned short* h2 = (unsigned short*)ws; ws += (size_t)NROWS * HID * 2; // h2 bf16
  float* norms = (float*)ws;                ws += (size_t)NROWS * 4;

  {
    int n8 = NROWS * INDIM / 8;
    cast_f32_fp8<<<(n8 + 255) / 256, 256, 0, stream>>>(x, xq, 16.f, n8);
    cast_f32_fp8<<<(n8 + 255) / 256, 256, 0, stream>>>(W1, w1q, 32.f, n8);
    int m8 = HID * HID / 8;
    cast_f32_fp8<<<(m8 + 255) / 256, 256, 0, stream>>>(W2, w2q, 128.f, m8);
  }

  const int grid = (NROWS / 256) * (HID / 256);  // 256

  // h1 = tanh((x16 @ W1_32^T)/512 + b1), stored as fp8(8*h1)
  gemm256_fp8<0><<<grid, 512, 0, stream>>>(xq, w1q, INDIM, HID, b1, h1q, nullptr);
  // out = bc; norms = 0
  init_vecs<<<(NROWS + 255) / 256, 256, 0, stream>>>(out, norms, bc, NROWS);
  // h2 = tanh((h1_8 @ W2_128^T)/1024 + b2) -> bf16, norms fused
  gemm256_fp8<2><<<grid, 512, 0, stream>>>(h1q, w2q, HID, HID, b2, h2, norms);
  // triangular gram + classifier (bf16)
  gram_tri<<<528, 256, 0, stream>>>(h2, HID, norms, Wc, out);
}

// Round 7
// 201.112 us; speedup vs baseline: 1.3611x; 1.3611x over previous
//
#include <hip/hip_runtime.h>
#include <hip/hip_bf16.h>

// FraudDetectionHybrid: h1=tanh(x@W1^T+b1); h2=tanh(h1@W2^T+b2);
// sq_ij=|h2_i|^2+|h2_j|^2-2*h2_i.h2_j; out=exp(-g*sq)@Wc^T+bc
// All-fp8 (e4m3, unit MX scales, data pre-scaled by 2^k).
// MFMA shape: 16x16x128 -> fragment reads replicate the PROVEN zero-conflict
// lane shape (row=lane&15, chunk=lane>>4 ^ swz, 64B rows). Lane's 32B operand
// split across two LDS regions (region h = h-th 16B of each 32B k-group),
// one standalone b128 per region. Gram: fp8 triangular 128^2.

#define NROWS 4096
#define HID   4096
#define INDIM 512
#define GAMMA_F 5e-4f

typedef float f32x4  __attribute__((ext_vector_type(4)));
typedef int   i32x4  __attribute__((ext_vector_type(4)));
typedef int   i32x8  __attribute__((ext_vector_type(8)));

#define BAR() asm volatile("s_barrier" ::: "memory")
#define SCALE1 0x7F7F7F7F   // e8m0 = 127 -> 2^0 in all bytes; opsel-independent

__device__ __forceinline__ unsigned short f2bf_rne(float f) {
  union { float f; unsigned int u; } v; v.f = f;
  unsigned int r = v.u + 0x7FFFu + ((v.u >> 16) & 1u);
  return (unsigned short)(r >> 16);
}

// f32 -> OCP e4m3fn, RNE, saturate to 448, subnormals handled
__device__ __forceinline__ unsigned char f2e4m3(float x) {
  unsigned int u = __float_as_uint(x);
  unsigned char s = (unsigned char)((u >> 24) & 0x80u);
  float a = fabsf(x);
  if (a >= 448.f) return s | 0x7E;
  if (a < 0.015625f) {                      // below 2^-6: subnormal (2^-9 ulp)
    int q = (int)rintf(a * 512.f);          // 0..8 (8 == 2^-6 encodes as 0x08)
    return s | (unsigned char)q;
  }
  unsigned int ua = u & 0x7fffffffu;
  ua += 0x7FFFFu + ((ua >> 20) & 1u);       // RNE at mantissa bit 20
  int e = (int)(ua >> 23) - 127;            // -6..8
  unsigned int m = (ua >> 20) & 7u;
  return s | (unsigned char)(((e + 7) << 3) | m);
}

__global__ void cast_f32_fp8(const float* __restrict__ src,
                             unsigned char* __restrict__ dst,
                             float scale, int n8) {
  int i = blockIdx.x * blockDim.x + threadIdx.x;
  if (i >= n8) return;
  const float4* s = (const float4*)src;
  float4 v0 = s[i * 2], v1 = s[i * 2 + 1];
  unsigned int r0 = (unsigned int)f2e4m3(v0.x * scale)
                  | ((unsigned int)f2e4m3(v0.y * scale) << 8)
                  | ((unsigned int)f2e4m3(v0.z * scale) << 16)
                  | ((unsigned int)f2e4m3(v0.w * scale) << 24);
  unsigned int r1 = (unsigned int)f2e4m3(v1.x * scale)
                  | ((unsigned int)f2e4m3(v1.y * scale) << 8)
                  | ((unsigned int)f2e4m3(v1.z * scale) << 16)
                  | ((unsigned int)f2e4m3(v1.w * scale) << 24);
  uint2 o; o.x = r0; o.y = r1;
  ((uint2*)dst)[i] = o;
}

__global__ void init_vecs(float* __restrict__ out, float* __restrict__ norms,
                          const float* __restrict__ bc, int n) {
  int i = blockIdx.x * blockDim.x + threadIdx.x;
  if (i < n) { out[i] = bc[0]; norms[i] = 0.f; }
}

__device__ __forceinline__ void gload16(const void* g, void* l) {
  __builtin_amdgcn_global_load_lds(
      (const __attribute__((address_space(1))) void*)g,
      (__attribute__((address_space(3))) void*)l, 16, 0, 0);
}

// ---------------------------------------------------------------------------
// fp8 NT GEMM: D = A[M,K]*B[N,K]^T (e4m3). BM=BN=256, BK=128 B, 8 waves
// (2Mx4N), wave tile 128x64 = 8mi x 4nj fragments of 16x16, K=128/MFMA.
// LDS per matrix: [dbuf][region h][256 rows][64B] = 64 KiB (128 KiB total).
//   region h holds the h-th 16B of each 32B k-group; within a region,
//   row r chunk c stores k-group c ^ ((r>>1)&3) (involution; pre-swizzled
//   global src, linear LDS dest). Fragment read = one b128 per region with
//   the PROVEN shape: row = base+lane&15, chunk = (lane>>4) ^ swz(row).
// 3 barriers/K-tile, counted vmcnt(8) (R6's verified hazard scheme):
//   S1: read A mi0-3 + B nj0-3 (16 b128) | lgkm,BAR | stage B(t+2) | 16 MFMA
//   S2: read A mi4-7 (8 b128) | lgkm,BAR | stage A(t+2) | 16 MFMA | vmcnt(8),BAR
// EPI 0: Hout(fp8) = e4m3(8*tanh(acc/512 + bias));
// EPI 2: Hout(fp8) = e4m3(8*tanh(acc/1024 + bias)) + row-norm atomics (f32 v).
// ---------------------------------------------------------------------------
template <int EPI>
__global__ __launch_bounds__(512, 2)
void gemm256_fp8(const unsigned char* __restrict__ A, const unsigned char* __restrict__ B,
                 int K, int N,
                 const float* __restrict__ bias, unsigned char* __restrict__ Hout,
                 float* __restrict__ norms_out) {
  __shared__ __align__(16) unsigned char As[2][2][256 * 64];
  __shared__ __align__(16) unsigned char Bs[2][2][256 * 64];

  const int tid  = threadIdx.x;
  const int lane = tid & 63;
  const int wave = tid >> 6;
  const int wr = wave >> 2, wc = wave & 3;   // 2x4 wave grid, 128x64 out each
  const int fr = lane & 15, fq = lane >> 4;

  const int nwg = gridDim.x;
  const int cpx = nwg >> 3;
  const int bid = blockIdx.x;
  const int swzb = (bid & 7) * cpx + (bid >> 3);
  const int nbx = N >> 8;
  const int brow = (swzb / nbx) << 8;
  const int bcol = (swzb % nbx) << 8;

  // staging: 2048 16B-chunks per matrix-tile; idx = q*512+tid ->
  // region h = idx>>10, row = (idx>>2)&255, c = idx&3;
  // global 16B col gc = ((c ^ swz(row))<<1) | h.
  const unsigned char* ap[4]; const unsigned char* bp[4]; int ldq[4];
#pragma unroll
  for (int q = 0; q < 4; ++q) {
    int idx = q * 512 + tid;
    int h   = idx >> 10;
    int row = (idx >> 2) & 255;
    int c   = idx & 3;
    int gcol = ((((c ^ ((row >> 1) & 3)) << 1) | h) << 4);
    ap[q] = A + (size_t)(brow + row) * K + gcol;
    bp[q] = B + (size_t)(bcol + row) * K + gcol;
    ldq[q] = (q * 512 + wave * 64) * 16;     // wave-uniform linear LDS base
  }
#define STAGE_A(p, tt) do { int kk = (tt) * 128;              \
    gload16(ap[0] + kk, &As[p][0][0] + ldq[0]);               \
    gload16(ap[1] + kk, &As[p][0][0] + ldq[1]);               \
    gload16(ap[2] + kk, &As[p][0][0] + ldq[2]);               \
    gload16(ap[3] + kk, &As[p][0][0] + ldq[3]); } while (0)
#define STAGE_B(p, tt) do { int kk = (tt) * 128;              \
    gload16(bp[0] + kk, &Bs[p][0][0] + ldq[0]);               \
    gload16(bp[1] + kk, &Bs[p][0][0] + ldq[1]);               \
    gload16(bp[2] + kk, &Bs[p][0][0] + ldq[2]);               \
    gload16(bp[3] + kk, &Bs[p][0][0] + ldq[3]); } while (0)

  // fragment offsets (proven shape): row = base + fr, chunk = fq ^ swz(row)
  int aoff[8], boff[4];
#pragma unroll
  for (int mi = 0; mi < 8; ++mi) {
    int row = wr * 128 + mi * 16 + fr;
    aoff[mi] = row * 64 + ((fq ^ ((row >> 1) & 3)) << 4);
  }
#pragma unroll
  for (int nj = 0; nj < 4; ++nj) {
    int row = wc * 64 + nj * 16 + fr;
    boff[nj] = row * 64 + ((fq ^ ((row >> 1) & 3)) << 4);
  }

  // operand: bytes 0-15 from region0, 16-31 from region1 (k = fq*32 + byte)
#define LDFRAG(dst, base0, off) do {                                \
    i32x4 lo_ = *(const i32x4*)((base0) + (off));                   \
    i32x4 hi_ = *(const i32x4*)((base0) + 16384 + (off));           \
    dst[0]=lo_[0]; dst[1]=lo_[1]; dst[2]=lo_[2]; dst[3]=lo_[3];     \
    dst[4]=hi_[0]; dst[5]=hi_[1]; dst[6]=hi_[2]; dst[7]=hi_[3]; } while (0)

#define MFMA16(d, a, b) \
    d = __builtin_amdgcn_mfma_scale_f32_16x16x128_f8f6f4( \
        a, b, d, 0, 0, 0, SCALE1, 0, SCALE1)

  const int NT = K >> 7;   // K-tiles of 128 bytes

  STAGE_A(0, 0); STAGE_B(0, 0);
  STAGE_A(1, 1); STAGE_B(1, 1);
  asm volatile("s_waitcnt vmcnt(8)" ::: "memory");   // tile0's 8 landed
  BAR();

  f32x4 acc[8][4] = {};
  i32x8 afr[4], bfr[4];

  for (int t = 0; t < NT; ++t) {
    const int p = t & 1;
    int t2 = t + 2; if (t2 >= NT) t2 -= NT;   // wrapped dummy keeps counts uniform

    // ---- S1: read A mi0-3 + B nj0-3 (16 b128) ----
#pragma unroll
    for (int mi = 0; mi < 4; ++mi) LDFRAG(afr[mi], &As[p][0][0], aoff[mi]);
#pragma unroll
    for (int nj = 0; nj < 4; ++nj) LDFRAG(bfr[nj], &Bs[p][0][0], boff[nj]);
    asm volatile("s_waitcnt lgkmcnt(0)" ::: "memory");
    BAR();                                   // all waves' B (and A03) reads done
    STAGE_B(p, t2);                          // safe to overwrite Bs[p]
    __builtin_amdgcn_sched_barrier(0);
    __builtin_amdgcn_s_setprio(1);
#pragma unroll
    for (int mi = 0; mi < 4; ++mi)
#pragma unroll
      for (int nj = 0; nj < 4; ++nj) MFMA16(acc[mi][nj], afr[mi], bfr[nj]);
    __builtin_amdgcn_s_setprio(0);

    // ---- S2: read A mi4-7 (8 b128, reuse afr) ----
#pragma unroll
    for (int mi = 0; mi < 4; ++mi) LDFRAG(afr[mi], &As[p][0][0], aoff[4 + mi]);
    asm volatile("s_waitcnt lgkmcnt(0)" ::: "memory");
    BAR();                                   // all waves' A reads done
    STAGE_A(p, t2);                          // safe to overwrite As[p]
    __builtin_amdgcn_sched_barrier(0);
    __builtin_amdgcn_s_setprio(1);
#pragma unroll
    for (int mi = 0; mi < 4; ++mi)
#pragma unroll
      for (int nj = 0; nj < 4; ++nj) MFMA16(acc[4 + mi][nj], afr[mi], bfr[nj]);
    __builtin_amdgcn_s_setprio(0);
    asm volatile("s_waitcnt vmcnt(8)" ::: "memory");    // t+1's 8 loads landed
    BAR();
  }
  asm volatile("s_waitcnt vmcnt(0)" ::: "memory");

  // C/D layout (16x16, shape-determined): col = lane&15, row = (lane>>4)*4+reg
  const float rescale = (EPI == 0) ? (1.f / 512.f) : (1.f / 1024.f);
  float bv[4];
#pragma unroll
  for (int nj = 0; nj < 4; ++nj) bv[nj] = bias[bcol + wc * 64 + nj * 16 + fr];
#pragma unroll
  for (int mi = 0; mi < 8; ++mi) {
    int row0 = brow + wr * 128 + mi * 16 + fq * 4;
#pragma unroll
    for (int rr = 0; rr < 4; ++rr) {
      float ns = 0.f;
#pragma unroll
      for (int nj = 0; nj < 4; ++nj) {
        int col = bcol + wc * 64 + nj * 16 + fr;
        float v = tanhf(acc[mi][nj][rr] * rescale + bv[nj]);
        Hout[(size_t)(row0 + rr) * N + col] = f2e4m3(8.f * v);
        if (EPI == 2) ns += v * v;
      }
      if (EPI == 2) {
        ns += __shfl_xor(ns, 1);
        ns += __shfl_xor(ns, 2);
        ns += __shfl_xor(ns, 4);
        ns += __shfl_xor(ns, 8);
        if (fr == 0) atomicAdd(&norms_out[row0 + rr], ns);
      }
    }
  }
#undef STAGE_A
#undef STAGE_B
#undef LDFRAG
#undef MFMA16
}

// ---------------------------------------------------------------------------
// Triangular gram, fp8: 128x128 tiles over the lower triangle (528 blocks),
// 4 waves (2x2), single-buffer 2-barrier loop. H is e4m3(8*h2): d = acc/64,
// sq = n_r + n_c - acc/32. Same 2-region LDS scheme (region stride 8192).
// ---------------------------------------------------------------------------
__global__ __launch_bounds__(256, 2)
void gram_tri(const unsigned char* __restrict__ H, int K,
              const float* __restrict__ norms, const float* __restrict__ Wc,
              float* __restrict__ out) {
  __shared__ __align__(16) unsigned char As[2][128 * 64];
  __shared__ __align__(16) unsigned char Bs[2][128 * 64];

  const int tid  = threadIdx.x;
  const int lane = tid & 63;
  const int wave = tid >> 6;
  const int wr = wave >> 1, wc = wave & 1;
  const int fr = lane & 15, fq = lane >> 4;

  const int bid = blockIdx.x;
  const int swzb = (bid & 7) * 66 + (bid >> 3);
  int I = (int)((sqrtf(8.0f * (float)swzb + 1.0f) - 1.0f) * 0.5f);
  while ((I + 1) * (I + 2) / 2 <= swzb) ++I;
  while (I * (I + 1) / 2 > swzb) --I;
  const int J = swzb - I * (I + 1) / 2;
  const int brow = I << 7, bcol = J << 7;
  const bool diag = (I == J);

  // staging: 1024 chunks per matrix-tile; idx = q*256+tid ->
  // h = idx>>9, row = (idx>>2)&127, c = idx&3
  const unsigned char* ap[4]; const unsigned char* bp[4]; int ldq[4];
#pragma unroll
  for (int q = 0; q < 4; ++q) {
    int idx = q * 256 + tid;
    int h   = idx >> 9;
    int row = (idx >> 2) & 127;
    int c   = idx & 3;
    int gcol = ((((c ^ ((row >> 1) & 3)) << 1) | h) << 4);
    ap[q] = H + (size_t)(brow + row) * K + gcol;
    bp[q] = H + (size_t)(bcol + row) * K + gcol;
    ldq[q] = (q * 256 + wave * 64) * 16;
  }

  int aoff[4], boff[4];
#pragma unroll
  for (int mi = 0; mi < 4; ++mi) {
    int row = wr * 64 + mi * 16 + fr;
    aoff[mi] = row * 64 + ((fq ^ ((row >> 1) & 3)) << 4);
  }
#pragma unroll
  for (int nj = 0; nj < 4; ++nj) {
    int row = wc * 64 + nj * 16 + fr;
    boff[nj] = row * 64 + ((fq ^ ((row >> 1) & 3)) << 4);
  }

#define LDFRAG(dst, base0, off) do {                                \
    i32x4 lo_ = *(const i32x4*)((base0) + (off));                   \
    i32x4 hi_ = *(const i32x4*)((base0) + 8192 + (off));            \
    dst[0]=lo_[0]; dst[1]=lo_[1]; dst[2]=lo_[2]; dst[3]=lo_[3];     \
    dst[4]=hi_[0]; dst[5]=hi_[1]; dst[6]=hi_[2]; dst[7]=hi_[3]; } while (0)

  f32x4 acc[4][4] = {};

  for (int t = 0; t < (K >> 7); ++t) {
    __syncthreads();
    {
      int kk = t * 128;
      gload16(ap[0] + kk, &As[0][0] + ldq[0]);
      gload16(ap[1] + kk, &As[0][0] + ldq[1]);
      gload16(ap[2] + kk, &As[0][0] + ldq[2]);
      gload16(ap[3] + kk, &As[0][0] + ldq[3]);
      gload16(bp[0] + kk, &Bs[0][0] + ldq[0]);
      gload16(bp[1] + kk, &Bs[0][0] + ldq[1]);
      gload16(bp[2] + kk, &Bs[0][0] + ldq[2]);
      gload16(bp[3] + kk, &Bs[0][0] + ldq[3]);
    }
    __syncthreads();   // implicit vmcnt(0) drain: staging landed

    i32x8 af[4], bf[4];
#pragma unroll
    for (int mi = 0; mi < 4; ++mi) LDFRAG(af[mi], &As[0][0], aoff[mi]);
#pragma unroll
    for (int nj = 0; nj < 4; ++nj) LDFRAG(bf[nj], &Bs[0][0], boff[nj]);
#pragma unroll
    for (int mi = 0; mi < 4; ++mi)
#pragma unroll
      for (int nj = 0; nj < 4; ++nj)
        acc[mi][nj] = __builtin_amdgcn_mfma_scale_f32_16x16x128_f8f6f4(
            af[mi], bf[nj], acc[mi][nj], 0, 0, 0, SCALE1, 0, SCALE1);
  }
#undef LDFRAG

  // epilogue: sq = n_r + n_c - acc/32 ; dual-direction reduction
  float ncol[4], wcv[4];
#pragma unroll
  for (int nj = 0; nj < 4; ++nj) {
    int col = bcol + wc * 64 + nj * 16 + fr;
    ncol[nj] = norms[col];
    wcv[nj]  = Wc[col];
  }
  float colpart[4] = {0.f, 0.f, 0.f, 0.f};
#pragma unroll
  for (int mi = 0; mi < 4; ++mi) {
    int row0 = brow + wr * 64 + mi * 16 + fq * 4;
    float4 nr4  = *(const float4*)&norms[row0];
    float4 wcr4 = *(const float4*)&Wc[row0];
#pragma unroll
    for (int rr = 0; rr < 4; ++rr) {
      float nrow = (rr == 0) ? nr4.x : (rr == 1) ? nr4.y : (rr == 2) ? nr4.z : nr4.w;
      float wrow = (rr == 0) ? wcr4.x : (rr == 1) ? wcr4.y : (rr == 2) ? wcr4.z : wcr4.w;
      float rowpart = 0.f;
#pragma unroll
      for (int nj = 0; nj < 4; ++nj) {
        float sq = nrow + ncol[nj] - acc[mi][nj][rr] * 0.03125f;
        float e = __expf(-GAMMA_F * sq);
        rowpart += e * wcv[nj];
        colpart[nj] += e * wrow;
      }
      rowpart += __shfl_xor(rowpart, 1);
      rowpart += __shfl_xor(rowpart, 2);
      rowpart += __shfl_xor(rowpart, 4);
      rowpart += __shfl_xor(rowpart, 8);
      if (fr == 0) atomicAdd(&out[row0 + rr], rowpart);
    }
  }
  if (!diag) {
#pragma unroll
    for (int nj = 0; nj < 4; ++nj) {
      colpart[nj] += __shfl_xor(colpart[nj], 16);
      colpart[nj] += __shfl_xor(colpart[nj], 32);
      if (fq == 0) atomicAdd(&out[bcol + wc * 64 + nj * 16 + fr], colpart[nj]);
    }
  }
}

extern "C" void kernel_launch(void* const* d_in, const int* in_sizes, int n_in,
                              void* d_out, int out_size, void* d_ws, size_t ws_size,
                              hipStream_t stream) {
  const float* x  = (const float*)d_in[0];  // [4096,512]
  const float* W1 = (const float*)d_in[1];  // [4096,512]
  const float* b1 = (const float*)d_in[2];  // [4096]
  const float* W2 = (const float*)d_in[3];  // [4096,4096]
  const float* b2 = (const float*)d_in[4];  // [4096]
  const float* Wc = (const float*)d_in[5];  // [1,4096]
  const float* bc = (const float*)d_in[6];  // [1]
  float* out = (float*)d_out;               // [4096,1]

  char* ws = (char*)d_ws;
  unsigned char* xq  = (unsigned char*)ws; ws += (size_t)NROWS * INDIM;   // x*16   fp8
  unsigned char* w1q = (unsigned char*)ws; ws += (size_t)HID * INDIM;     // W1*32  fp8
  unsigned char* w2q = (unsigned char*)ws; ws += (size_t)HID * HID;       // W2*128 fp8
  unsigned char* h1q = (unsigned char*)ws; ws += (size_t)NROWS * HID;     // h1*8   fp8
  unsigned char* h2q = (unsigned char*)ws; ws += (size_t)NROWS * HID;     // h2*8   fp8
  float* norms = (float*)ws;                ws += (size_t)NROWS * 4;

  {
    int n8 = NROWS * INDIM / 8;
    cast_f32_fp8<<<(n8 + 255) / 256, 256, 0, stream>>>(x, xq, 16.f, n8);
    cast_f32_fp8<<<(n8 + 255) / 256, 256, 0, stream>>>(W1, w1q, 32.f, n8);
    int m8 = HID * HID / 8;
    cast_f32_fp8<<<(m8 + 255) / 256, 256, 0, stream>>>(W2, w2q, 128.f, m8);
  }

  const int grid = (NROWS / 256) * (HID / 256);  // 256

  // h1 = tanh((x16 @ W1_32^T)/512 + b1) -> fp8(8*h1)
  gemm256_fp8<0><<<grid, 512, 0, stream>>>(xq, w1q, INDIM, HID, b1, h1q, nullptr);
  // out = bc; norms = 0
  init_vecs<<<(NROWS + 255) / 256, 256, 0, stream>>>(out, norms, bc, NROWS);
  // h2 = tanh((h1_8 @ W2_128^T)/1024 + b2) -> fp8(8*h2), norms (f32) fused
  gemm256_fp8<2><<<grid, 512, 0, stream>>>(h1q, w2q, HID, HID, b2, h2q, norms);
  // triangular gram + classifier (fp8)
  gram_tri<<<528, 256, 0, stream>>>(h2q, HID, norms, Wc, out);
}